// Round 6
// baseline (222.825 us; speedup 1.0000x reference)
//
#include <hip/hip_runtime.h>
#include <math.h>

constexpr int DIM    = 768;
constexpr int NHEADS = 12;
constexpr int HD     = 64;
constexpr int BATCH  = 8;
constexpr int SEQ    = 1024;
constexpr float SCALE = 0.125f;           // HEAD_DIM^-0.5
constexpr float QSCALE = 0.18033688011112042f;  // SCALE * log2(e), baked into q

typedef __attribute__((ext_vector_type(8))) short short8;   // 8 bf16 (4 VGPRs)
typedef __attribute__((ext_vector_type(4))) float f32x4;    // MFMA accumulator

static __device__ __forceinline__ unsigned short f2bf(float f) {
  unsigned int u = __float_as_uint(f);
  return (unsigned short)((u + 0x7fffu + ((u >> 16) & 1u)) >> 16);  // RNE
}
static __device__ __forceinline__ float bf2f(unsigned short h) {
  return __uint_as_float((unsigned int)h << 16);
}

// async global->LDS, 16B per lane; LDS dest = wave-uniform base + lane*16
#define GLLD16(gp, lp) __builtin_amdgcn_global_load_lds(                    \
    (__attribute__((address_space(1))) void*)(gp),                          \
    (__attribute__((address_space(3))) void*)(lp), 16, 0, 0)

// ---------------------------------------------------------------------------
// Fused prep: convert x and qkv_w to bf16; decompose proj_w to hi/lo.
// ---------------------------------------------------------------------------
constexpr int NX4 = BATCH * SEQ * DIM / 4;      // 1572864
constexpr int NQ4 = 3 * DIM * DIM / 4;          // 442368
constexpr int NP4 = DIM * DIM / 4;              // 147456

__global__ __launch_bounds__(256) void prep_all(
    const float* __restrict__ x, const float* __restrict__ qkv_w,
    const float* __restrict__ proj_w,
    unsigned short* __restrict__ x_bf, unsigned short* __restrict__ qw_bf,
    unsigned short* __restrict__ pw_hi, unsigned short* __restrict__ pw_lo)
{
  int gid = blockIdx.x * 256 + threadIdx.x;
  if (gid < NX4) {
    float4 v = ((const float4*)x)[gid];
    ushort4 h;
    h.x = f2bf(v.x); h.y = f2bf(v.y); h.z = f2bf(v.z); h.w = f2bf(v.w);
    ((ushort4*)x_bf)[gid] = h;
  } else if (gid < NX4 + NQ4) {
    int i = gid - NX4;
    float4 v = ((const float4*)qkv_w)[i];
    ushort4 h;
    h.x = f2bf(v.x); h.y = f2bf(v.y); h.z = f2bf(v.z); h.w = f2bf(v.w);
    ((ushort4*)qw_bf)[i] = h;
  } else if (gid < NX4 + NQ4 + NP4) {
    int i = gid - NX4 - NQ4;
    float4 v = ((const float4*)proj_w)[i];
    ushort4 h, l;
    h.x = f2bf(v.x); l.x = f2bf(v.x - bf2f(h.x));
    h.y = f2bf(v.y); l.y = f2bf(v.y - bf2f(h.y));
    h.z = f2bf(v.z); l.z = f2bf(v.z - bf2f(h.z));
    h.w = f2bf(v.w); l.w = f2bf(v.w - bf2f(h.w));
    ((ushort4*)pw_hi)[i] = h;
    ((ushort4*)pw_lo)[i] = l;
  }
}

// ---------------------------------------------------------------------------
// MFMA GEMM, global_load_lds staging + XOR-swizzled K-chunks.
//   C[M,N] = sum_seg A_seg[M,K] * B_seg[N,K]^T,  K = 768, BK = 64
// Tile 128 x BN, 256 threads = 4 waves (2x2), wave tile 64 x BN/2.
// QKV_EPI: q written *QSCALE-scaled* [b,h,n,d]; k [b,h,n,d]; v TRANSPOSED
//          [b,h,d,n] (packed ushort4 along n).
// ---------------------------------------------------------------------------
template<int BN, int SEGS, bool QKV_EPI>
__global__ __launch_bounds__(256) void gemm_mfma_glld(
    const unsigned short* __restrict__ A0, const unsigned short* __restrict__ A1,
    const unsigned short* __restrict__ B0, const unsigned short* __restrict__ B1,
    const float* __restrict__ bias,
    unsigned short* __restrict__ q_bf, unsigned short* __restrict__ k_bf,
    unsigned short* __restrict__ v_t, float* __restrict__ out)
{
  constexpr int K = DIM, BK = 64;
  constexpr int NB = BN / 32;
  __shared__ __align__(16) unsigned short Abuf[128 * BK];
  __shared__ __align__(16) unsigned short Bbuf[BN * BK];

  const int tid  = threadIdx.x;
  const int wave = tid >> 6, lane = tid & 63;
  const int quad = lane >> 4, l16 = lane & 15;
  const int wm = wave >> 1, wn = wave & 1;
  const int m0 = blockIdx.x * 128, n0 = blockIdx.y * BN;

  f32x4 acc[4][NB] = {};

  #pragma unroll 1
  for (int seg = 0; seg < SEGS; ++seg) {
    const unsigned short* Asrc = (seg == 1) ? A1 : A0;
    const unsigned short* Bsrc = (seg == 2) ? B1 : B0;
    const unsigned short* ga = Asrc + (size_t)m0 * K;
    const unsigned short* gb = Bsrc + (size_t)n0 * K;

    #pragma unroll 1
    for (int k0 = 0; k0 < K; k0 += BK) {
      #pragma unroll
      for (int i = 0; i < 4; ++i) {
        int c = i * 256 + tid;
        int row = c >> 3;
        int col = ((c & 7) ^ (row & 7)) * 8;           // XOR swizzle
        GLLD16(ga + (size_t)row * K + k0 + col,
               Abuf + (size_t)(i * 256 + wave * 64) * 8);
      }
      #pragma unroll
      for (int i = 0; i < BN / 32; ++i) {
        int c = i * 256 + tid;
        int row = c >> 3;
        int col = ((c & 7) ^ (row & 7)) * 8;
        GLLD16(gb + (size_t)row * K + k0 + col,
               Bbuf + (size_t)(i * 256 + wave * 64) * 8);
      }
      __syncthreads();

      #pragma unroll
      for (int s = 0; s < 2; ++s) {
        short8 af[4], bfr[NB];
        #pragma unroll
        for (int mb = 0; mb < 4; ++mb) {
          int row = wm * 64 + mb * 16 + l16;
          int cg = (s * 4 + quad) ^ (row & 7);
          af[mb] = *(const short8*)&Abuf[row * BK + cg * 8];
        }
        #pragma unroll
        for (int nb = 0; nb < NB; ++nb) {
          int row = wn * (BN / 2) + nb * 16 + l16;
          int cg = (s * 4 + quad) ^ (row & 7);
          bfr[nb] = *(const short8*)&Bbuf[row * BK + cg * 8];
        }
        #pragma unroll
        for (int mb = 0; mb < 4; ++mb)
          #pragma unroll
          for (int nb = 0; nb < NB; ++nb)
            acc[mb][nb] = __builtin_amdgcn_mfma_f32_16x16x32_bf16(
                af[mb], bfr[nb], acc[mb][nb], 0, 0, 0);
      }
      __syncthreads();
    }
  }

  if (QKV_EPI) {
    #pragma unroll
    for (int nb = 0; nb < NB; ++nb) {
      int n = n0 + wn * (BN / 2) + nb * 16 + l16;
      int t = n / DIM, rem = n % DIM;   // t uniform per block-column
      int h = rem >> 6, d = rem & 63;
      if (t == 2) {
        // V transposed [b,h,d,n]: 4 consecutive n per lane -> packed store
        #pragma unroll
        for (int mb = 0; mb < 4; ++mb) {
          int mb_base = m0 + wm * 64 + mb * 16 + quad * 4;
          int bb = mb_base >> 10, nn = mb_base & 1023;
          ushort4 s4;
          s4.x = f2bf(acc[mb][nb][0]); s4.y = f2bf(acc[mb][nb][1]);
          s4.z = f2bf(acc[mb][nb][2]); s4.w = f2bf(acc[mb][nb][3]);
          *(ushort4*)&v_t[(((size_t)(bb * NHEADS + h) * HD + d) << 10) + nn] = s4;
        }
      } else {
        unsigned short* dst = (t == 0) ? q_bf : k_bf;
        float sc = (t == 0) ? QSCALE : 1.f;   // bake softmax scale into q
        #pragma unroll
        for (int mb = 0; mb < 4; ++mb) {
          #pragma unroll
          for (int r = 0; r < 4; ++r) {
            int m = m0 + wm * 64 + mb * 16 + quad * 4 + r;
            int bb = m >> 10, nn = m & 1023;
            dst[(((size_t)(bb * NHEADS + h) << 10) + nn) * HD + d] =
                f2bf(acc[mb][nb][r] * sc);
          }
        }
      }
    }
  } else {
    #pragma unroll
    for (int nb = 0; nb < NB; ++nb) {
      int n = n0 + wn * (BN / 2) + nb * 16 + l16;
      float bv = bias[n];
      #pragma unroll
      for (int mb = 0; mb < 4; ++mb) {
        #pragma unroll
        for (int r = 0; r < 4; ++r) {
          int m = m0 + wm * 64 + mb * 16 + quad * 4 + r;
          out[(size_t)m * DIM + n] = acc[mb][nb][r] + bv;
        }
      }
    }
  }
}

// ---------------------------------------------------------------------------
// Flash attention, bf16 MFMA, fixed-max softmax (scores pre-scaled into q;
// p = exp2(s) directly). K [b,h,n,d] and V [b,h,d,n] both staged via
// global_load_lds with XOR swizzle -- no VALU transpose, no pads.
// l accumulated by ones-column MFMA over the same truncated-bf16 P.
// LDS = 8K + 8K + 9.2K = 25.6 KB -> 6 blocks/CU -> all 1536 blocks resident.
// ---------------------------------------------------------------------------
__global__ __launch_bounds__(256) void flash_attn_mfma(
    const unsigned short* __restrict__ q_bf,   // [b,h,n,d], pre-scaled
    const unsigned short* __restrict__ k_bf,   // [b,h,n,d]
    const unsigned short* __restrict__ v_t,    // [b,h,d,n]
    unsigned short* __restrict__ attn_hi,
    unsigned short* __restrict__ attn_lo)
{
  constexpr int KT = 64;
  __shared__ __align__(16) unsigned short Ks[KT * HD];     // [key][d] swizzled
  __shared__ __align__(16) unsigned short Vs[HD * KT];     // [d][key] swizzled
  __shared__ __align__(16) unsigned short Ps[4][16][KT + 8];

  const int tid  = threadIdx.x;
  const int wave = tid >> 6, lane = tid & 63;
  const int quad = lane >> 4, l16 = lane & 15;
  const int bh = blockIdx.y;                  // q-tiles of a head contiguous
  const int b = bh / NHEADS, h = bh % NHEADS;
  const int q0 = blockIdx.x * 64;
  const size_t head_base = (size_t)bh << 16;  // bh * 1024 * 64

  short8 aq[2];
  {
    const unsigned short* qs = q_bf + head_base + (size_t)(q0 + wave * 16 + l16) * HD;
    aq[0] = *(const short8*)&qs[quad * 8];
    aq[1] = *(const short8*)&qs[32 + quad * 8];
  }
  short8 bv1;   // ones column n==0: lane l16==0 holds 1.0 for all k
  {
    short one = (l16 == 0) ? (short)0x3f80 : (short)0;
    #pragma unroll
    for (int j = 0; j < 8; ++j) bv1[j] = one;
  }

  f32x4 Oacc[4] = {};
  f32x4 Lacc = {};

  for (int kt = 0; kt < SEQ / KT; ++kt) {
    const unsigned short* ks = k_bf + head_base + (size_t)kt * KT * HD;
    const unsigned short* vs = v_t + head_base + (size_t)kt * KT;
    #pragma unroll
    for (int i = 0; i < 2; ++i) {
      int c = i * 256 + tid;
      int row = c >> 3;
      int col = ((c & 7) ^ (row & 7)) * 8;
      GLLD16(ks + (size_t)row * HD + col, Ks + (size_t)(i * 256 + wave * 64) * 8);
    }
    #pragma unroll
    for (int i = 0; i < 2; ++i) {
      int c = i * 256 + tid;
      int row = c >> 3;                        // d index
      int col = ((c & 7) ^ (row & 7)) * 8;     // key offset within tile
      GLLD16(vs + (size_t)row * SEQ + col, Vs + (size_t)(i * 256 + wave * 64) * 8);
    }
    __syncthreads();

    // S = Q * K^T  (pre-scaled: s = q.k * SCALE * log2e)
    f32x4 Sacc[4] = {};
    #pragma unroll
    for (int kb = 0; kb < 4; ++kb) {
      #pragma unroll
      for (int s = 0; s < 2; ++s) {
        int row = kb * 16 + l16;
        int slot = (s * 4 + quad) ^ (l16 & 7);
        short8 bk = *(const short8*)&Ks[row * HD + slot * 8];
        Sacc[kb] = __builtin_amdgcn_mfma_f32_16x16x32_bf16(aq[s], bk, Sacc[kb], 0, 0, 0);
      }
    }

    // p = 2^s, truncate to bf16, wave-private LDS
    #pragma unroll
    for (int kb = 0; kb < 4; ++kb) {
      #pragma unroll
      for (int i = 0; i < 4; ++i) {
        float p = exp2f(Sacc[kb][i]);
        Ps[wave][quad * 4 + i][kb * 16 + l16] =
            (unsigned short)(__float_as_uint(p) >> 16);
      }
    }

    // O += P*V ; l += P*ones  (same pa operand -> consistency)
    short8 pa[2];
    pa[0] = *(const short8*)&Ps[wave][l16][quad * 8];
    pa[1] = *(const short8*)&Ps[wave][l16][32 + quad * 8];
    #pragma unroll
    for (int db = 0; db < 4; ++db) {
      #pragma unroll
      for (int s = 0; s < 2; ++s) {
        int row = db * 16 + l16;               // d index
        int slot = (s * 4 + quad) ^ (l16 & 7);
        short8 bv = *(const short8*)&Vs[row * KT + slot * 8];
        Oacc[db] = __builtin_amdgcn_mfma_f32_16x16x32_bf16(pa[s], bv, Oacc[db], 0, 0, 0);
      }
    }
    #pragma unroll
    for (int s = 0; s < 2; ++s)
      Lacc = __builtin_amdgcn_mfma_f32_16x16x32_bf16(pa[s], bv1, Lacc, 0, 0, 0);

    __syncthreads();
  }

  // l for row quad*4+i lives in lane quad*16+0, reg i
  float linv[4];
  #pragma unroll
  for (int i = 0; i < 4; ++i) {
    float lv = __shfl(Lacc[i], quad << 4, 64);
    linv[i] = 1.f / lv;
  }
  #pragma unroll
  for (int i = 0; i < 4; ++i) {
    int n = q0 + wave * 16 + quad * 4 + i;
    size_t row = ((size_t)(b << 10) + n) * DIM + h * HD;
    #pragma unroll
    for (int db = 0; db < 4; ++db) {
      float val = Oacc[db][i] * linv[i];
      unsigned short hv = f2bf(val);
      attn_hi[row + db * 16 + l16] = hv;
      attn_lo[row + db * 16 + l16] = f2bf(val - bf2f(hv));
    }
  }
}

// ---------------------------------------------------------------------------
extern "C" void kernel_launch(void* const* d_in, const int* in_sizes, int n_in,
                              void* d_out, int out_size, void* d_ws, size_t ws_size,
                              hipStream_t stream)
{
  const float* x      = (const float*)d_in[0];   // [8,1024,768]
  const float* qkv_w  = (const float*)d_in[1];   // [2304,768]
  const float* proj_w = (const float*)d_in[2];   // [768,768]
  const float* proj_b = (const float*)d_in[3];   // [768]
  float* out = (float*)d_out;                    // [8,1024,768]

  const int M = BATCH * SEQ;                           // 8192
  const size_t he = (size_t)BATCH * NHEADS * SEQ * HD; // 6.29M = 8192*768

  unsigned short* q_bf  = (unsigned short*)d_ws;
  unsigned short* k_bf  = q_bf + he;
  unsigned short* v_t   = k_bf + he;                   // [b,h,d,n]
  unsigned short* x_bf  = v_t + he;                    // [8192,768] bf16
  unsigned short* qw_bf = x_bf + he;                   // [2304,768] bf16
  unsigned short* pw_hi = qw_bf + (size_t)3 * DIM * DIM;
  unsigned short* pw_lo = pw_hi + (size_t)DIM * DIM;
  unsigned short* a_hi  = pw_lo + (size_t)DIM * DIM;   // attn out hi [8192,768]
  unsigned short* a_lo  = a_hi + he;

  // 0) fused prep
  prep_all<<<(NX4 + NQ4 + NP4 + 255) / 256, 256, 0, stream>>>(
      x, qkv_w, proj_w, x_bf, qw_bf, pw_hi, pw_lo);

  // 1) QKV projection: single-pass bf16 MFMA, glld staging,
  //    writes scaled-q / k [b,h,n,d] and v transposed [b,h,d,n]
  gemm_mfma_glld<128, 1, true><<<dim3(M / 128, 3 * DIM / 128), 256, 0, stream>>>(
      x_bf, nullptr, qw_bf, nullptr, nullptr, q_bf, k_bf, v_t, nullptr);

  // 2) Flash attention (bf16 MFMA, fixed-max softmax, all-glld staging)
  flash_attn_mfma<<<dim3(SEQ / 64, BATCH * NHEADS), 256, 0, stream>>>(
      q_bf, k_bf, v_t, a_hi, a_lo);

  // 3) Output projection: 3-pass split-bf16 MFMA + bias, fp32 out
  gemm_mfma_glld<64, 3, false><<<dim3(M / 128, DIM / 64), 256, 0, stream>>>(
      a_hi, a_lo, pw_hi, pw_lo, proj_b, nullptr, nullptr, nullptr, out);
}

// Round 7
// 219.643 us; speedup vs baseline: 1.0145x; 1.0145x over previous
//
#include <hip/hip_runtime.h>
#include <math.h>

constexpr int DIM    = 768;
constexpr int NHEADS = 12;
constexpr int HD     = 64;
constexpr int BATCH  = 8;
constexpr int SEQ    = 1024;
constexpr float SCALE = 0.125f;           // HEAD_DIM^-0.5
constexpr float QSCALE = 0.18033688011112042f;  // SCALE * log2(e), baked into q

typedef __attribute__((ext_vector_type(8))) short short8;   // 8 bf16 (4 VGPRs)
typedef __attribute__((ext_vector_type(4))) float f32x4;    // MFMA accumulator

static __device__ __forceinline__ unsigned short f2bf(float f) {
  unsigned int u = __float_as_uint(f);
  return (unsigned short)((u + 0x7fffu + ((u >> 16) & 1u)) >> 16);  // RNE
}
static __device__ __forceinline__ float bf2f(unsigned short h) {
  return __uint_as_float((unsigned int)h << 16);
}

// async global->LDS, 16B per lane; LDS dest = wave-uniform base + lane*16
#define GLLD16(gp, lp) __builtin_amdgcn_global_load_lds(                    \
    (__attribute__((address_space(1))) void*)(gp),                          \
    (__attribute__((address_space(3))) void*)(lp), 16, 0, 0)

// ---------------------------------------------------------------------------
// Fused prep: convert x and qkv_w to bf16; decompose proj_w to hi/lo.
// ---------------------------------------------------------------------------
constexpr int NX4 = BATCH * SEQ * DIM / 4;      // 1572864
constexpr int NQ4 = 3 * DIM * DIM / 4;          // 442368
constexpr int NP4 = DIM * DIM / 4;              // 147456

__global__ __launch_bounds__(256) void prep_all(
    const float* __restrict__ x, const float* __restrict__ qkv_w,
    const float* __restrict__ proj_w,
    unsigned short* __restrict__ x_bf, unsigned short* __restrict__ qw_bf,
    unsigned short* __restrict__ pw_hi, unsigned short* __restrict__ pw_lo)
{
  int gid = blockIdx.x * 256 + threadIdx.x;
  if (gid < NX4) {
    float4 v = ((const float4*)x)[gid];
    ushort4 h;
    h.x = f2bf(v.x); h.y = f2bf(v.y); h.z = f2bf(v.z); h.w = f2bf(v.w);
    ((ushort4*)x_bf)[gid] = h;
  } else if (gid < NX4 + NQ4) {
    int i = gid - NX4;
    float4 v = ((const float4*)qkv_w)[i];
    ushort4 h;
    h.x = f2bf(v.x); h.y = f2bf(v.y); h.z = f2bf(v.z); h.w = f2bf(v.w);
    ((ushort4*)qw_bf)[i] = h;
  } else if (gid < NX4 + NQ4 + NP4) {
    int i = gid - NX4 - NQ4;
    float4 v = ((const float4*)proj_w)[i];
    ushort4 h, l;
    h.x = f2bf(v.x); l.x = f2bf(v.x - bf2f(h.x));
    h.y = f2bf(v.y); l.y = f2bf(v.y - bf2f(h.y));
    h.z = f2bf(v.z); l.z = f2bf(v.z - bf2f(h.z));
    h.w = f2bf(v.w); l.w = f2bf(v.w - bf2f(h.w));
    ((ushort4*)pw_hi)[i] = h;
    ((ushort4*)pw_lo)[i] = l;
  }
}

// ---------------------------------------------------------------------------
// MFMA GEMM, global_load_lds staging + XOR-swizzled K-chunks.
//   C[M,N] = sum_seg A_seg[M,K] * B_seg[N,K]^T,  K = 768, BK = 64
// Tile 128 x BN, 256 threads = 4 waves (2x2), wave tile 64 x BN/2.
// QKV_EPI: q written *QSCALE-scaled* [b,h,n,d]; k [b,h,n,d]; v TRANSPOSED
//          [b,h,d,n] (packed ushort4 along n).
// ---------------------------------------------------------------------------
template<int BN, int SEGS, bool QKV_EPI>
__global__ __launch_bounds__(256) void gemm_mfma_glld(
    const unsigned short* __restrict__ A0, const unsigned short* __restrict__ A1,
    const unsigned short* __restrict__ B0, const unsigned short* __restrict__ B1,
    const float* __restrict__ bias,
    unsigned short* __restrict__ q_bf, unsigned short* __restrict__ k_bf,
    unsigned short* __restrict__ v_t, float* __restrict__ out)
{
  constexpr int K = DIM, BK = 64;
  constexpr int NB = BN / 32;
  __shared__ __align__(16) unsigned short Abuf[128 * BK];
  __shared__ __align__(16) unsigned short Bbuf[BN * BK];

  const int tid  = threadIdx.x;
  const int wave = tid >> 6, lane = tid & 63;
  const int quad = lane >> 4, l16 = lane & 15;
  const int wm = wave >> 1, wn = wave & 1;
  const int m0 = blockIdx.x * 128, n0 = blockIdx.y * BN;

  f32x4 acc[4][NB] = {};

  #pragma unroll 1
  for (int seg = 0; seg < SEGS; ++seg) {
    const unsigned short* Asrc = (seg == 1) ? A1 : A0;
    const unsigned short* Bsrc = (seg == 2) ? B1 : B0;
    const unsigned short* ga = Asrc + (size_t)m0 * K;
    const unsigned short* gb = Bsrc + (size_t)n0 * K;

    #pragma unroll 1
    for (int k0 = 0; k0 < K; k0 += BK) {
      #pragma unroll
      for (int i = 0; i < 4; ++i) {
        int c = i * 256 + tid;
        int row = c >> 3;
        int col = ((c & 7) ^ (row & 7)) * 8;           // XOR swizzle
        GLLD16(ga + (size_t)row * K + k0 + col,
               Abuf + (size_t)(i * 256 + wave * 64) * 8);
      }
      #pragma unroll
      for (int i = 0; i < BN / 32; ++i) {
        int c = i * 256 + tid;
        int row = c >> 3;
        int col = ((c & 7) ^ (row & 7)) * 8;
        GLLD16(gb + (size_t)row * K + k0 + col,
               Bbuf + (size_t)(i * 256 + wave * 64) * 8);
      }
      __syncthreads();

      #pragma unroll
      for (int s = 0; s < 2; ++s) {
        short8 af[4], bfr[NB];
        #pragma unroll
        for (int mb = 0; mb < 4; ++mb) {
          int row = wm * 64 + mb * 16 + l16;
          int cg = (s * 4 + quad) ^ (row & 7);
          af[mb] = *(const short8*)&Abuf[row * BK + cg * 8];
        }
        #pragma unroll
        for (int nb = 0; nb < NB; ++nb) {
          int row = wn * (BN / 2) + nb * 16 + l16;
          int cg = (s * 4 + quad) ^ (row & 7);
          bfr[nb] = *(const short8*)&Bbuf[row * BK + cg * 8];
        }
        #pragma unroll
        for (int mb = 0; mb < 4; ++mb)
          #pragma unroll
          for (int nb = 0; nb < NB; ++nb)
            acc[mb][nb] = __builtin_amdgcn_mfma_f32_16x16x32_bf16(
                af[mb], bfr[nb], acc[mb][nb], 0, 0, 0);
      }
      __syncthreads();
    }
  }

  if (QKV_EPI) {
    #pragma unroll
    for (int nb = 0; nb < NB; ++nb) {
      int n = n0 + wn * (BN / 2) + nb * 16 + l16;
      int t = n / DIM, rem = n % DIM;   // t uniform per block-column
      int h = rem >> 6, d = rem & 63;
      if (t == 2) {
        // V transposed [b,h,d,n]: 4 consecutive n per lane -> packed store
        #pragma unroll
        for (int mb = 0; mb < 4; ++mb) {
          int mb_base = m0 + wm * 64 + mb * 16 + quad * 4;
          int bb = mb_base >> 10, nn = mb_base & 1023;
          ushort4 s4;
          s4.x = f2bf(acc[mb][nb][0]); s4.y = f2bf(acc[mb][nb][1]);
          s4.z = f2bf(acc[mb][nb][2]); s4.w = f2bf(acc[mb][nb][3]);
          *(ushort4*)&v_t[(((size_t)(bb * NHEADS + h) * HD + d) << 10) + nn] = s4;
        }
      } else {
        unsigned short* dst = (t == 0) ? q_bf : k_bf;
        float sc = (t == 0) ? QSCALE : 1.f;   // bake softmax scale into q
        #pragma unroll
        for (int mb = 0; mb < 4; ++mb) {
          #pragma unroll
          for (int r = 0; r < 4; ++r) {
            int m = m0 + wm * 64 + mb * 16 + quad * 4 + r;
            int bb = m >> 10, nn = m & 1023;
            dst[(((size_t)(bb * NHEADS + h) << 10) + nn) * HD + d] =
                f2bf(acc[mb][nb][r] * sc);
          }
        }
      }
    }
  } else {
    #pragma unroll
    for (int nb = 0; nb < NB; ++nb) {
      int n = n0 + wn * (BN / 2) + nb * 16 + l16;
      float bv = bias[n];
      #pragma unroll
      for (int mb = 0; mb < 4; ++mb) {
        #pragma unroll
        for (int r = 0; r < 4; ++r) {
          int m = m0 + wm * 64 + mb * 16 + quad * 4 + r;
          out[(size_t)m * DIM + n] = acc[mb][nb][r] + bv;
        }
      }
    }
  }
}

// ---------------------------------------------------------------------------
// Flash attention, bf16 MFMA, fixed-max softmax (scores pre-scaled into q;
// p = exp2(s) directly). K [b,h,n,d] and V [b,h,d,n] both staged via
// global_load_lds with XOR swizzle -- no VALU transpose, no pads.
// Grid: (x = head, y = q-tile). 96 heads % 8 XCDs == 0 -> every q-tile of a
// head lands on the SAME XCD, so each head's 262 KB K/V is HBM-fetched once
// and L2-served 15x (R6's swapped grid tripled FETCH_SIZE -- measured).
// ---------------------------------------------------------------------------
__global__ __launch_bounds__(256) void flash_attn_mfma(
    const unsigned short* __restrict__ q_bf,   // [b,h,n,d], pre-scaled
    const unsigned short* __restrict__ k_bf,   // [b,h,n,d]
    const unsigned short* __restrict__ v_t,    // [b,h,d,n]
    unsigned short* __restrict__ attn_hi,
    unsigned short* __restrict__ attn_lo)
{
  constexpr int KT = 64;
  __shared__ __align__(16) unsigned short Ks[KT * HD];     // [key][d] swizzled
  __shared__ __align__(16) unsigned short Vs[HD * KT];     // [d][key] swizzled
  __shared__ __align__(16) unsigned short Ps[4][16][KT + 8];

  const int tid  = threadIdx.x;
  const int wave = tid >> 6, lane = tid & 63;
  const int quad = lane >> 4, l16 = lane & 15;
  const int bh = blockIdx.x;                  // head on x -> XCD affinity
  const int b = bh / NHEADS, h = bh % NHEADS;
  const int q0 = blockIdx.y * 64;
  const size_t head_base = (size_t)bh << 16;  // bh * 1024 * 64

  short8 aq[2];
  {
    const unsigned short* qs = q_bf + head_base + (size_t)(q0 + wave * 16 + l16) * HD;
    aq[0] = *(const short8*)&qs[quad * 8];
    aq[1] = *(const short8*)&qs[32 + quad * 8];
  }
  short8 bv1;   // ones column n==0: lane l16==0 holds 1.0 for all k
  {
    short one = (l16 == 0) ? (short)0x3f80 : (short)0;
    #pragma unroll
    for (int j = 0; j < 8; ++j) bv1[j] = one;
  }

  f32x4 Oacc[4] = {};
  f32x4 Lacc = {};

  for (int kt = 0; kt < SEQ / KT; ++kt) {
    const unsigned short* ks = k_bf + head_base + (size_t)kt * KT * HD;
    const unsigned short* vs = v_t + head_base + (size_t)kt * KT;
    #pragma unroll
    for (int i = 0; i < 2; ++i) {
      int c = i * 256 + tid;
      int row = c >> 3;
      int col = ((c & 7) ^ (row & 7)) * 8;
      GLLD16(ks + (size_t)row * HD + col, Ks + (size_t)(i * 256 + wave * 64) * 8);
    }
    #pragma unroll
    for (int i = 0; i < 2; ++i) {
      int c = i * 256 + tid;
      int row = c >> 3;                        // d index
      int col = ((c & 7) ^ (row & 7)) * 8;     // key offset within tile
      GLLD16(vs + (size_t)row * SEQ + col, Vs + (size_t)(i * 256 + wave * 64) * 8);
    }
    __syncthreads();

    // S = Q * K^T  (pre-scaled: s = q.k * SCALE * log2e)
    f32x4 Sacc[4] = {};
    #pragma unroll
    for (int kb = 0; kb < 4; ++kb) {
      #pragma unroll
      for (int s = 0; s < 2; ++s) {
        int row = kb * 16 + l16;
        int slot = (s * 4 + quad) ^ (l16 & 7);
        short8 bk = *(const short8*)&Ks[row * HD + slot * 8];
        Sacc[kb] = __builtin_amdgcn_mfma_f32_16x16x32_bf16(aq[s], bk, Sacc[kb], 0, 0, 0);
      }
    }

    // p = 2^s, truncate to bf16, wave-private LDS
    #pragma unroll
    for (int kb = 0; kb < 4; ++kb) {
      #pragma unroll
      for (int i = 0; i < 4; ++i) {
        float p = exp2f(Sacc[kb][i]);
        Ps[wave][quad * 4 + i][kb * 16 + l16] =
            (unsigned short)(__float_as_uint(p) >> 16);
      }
    }

    // O += P*V ; l += P*ones  (same pa operand -> consistency)
    short8 pa[2];
    pa[0] = *(const short8*)&Ps[wave][l16][quad * 8];
    pa[1] = *(const short8*)&Ps[wave][l16][32 + quad * 8];
    #pragma unroll
    for (int db = 0; db < 4; ++db) {
      #pragma unroll
      for (int s = 0; s < 2; ++s) {
        int row = db * 16 + l16;               // d index
        int slot = (s * 4 + quad) ^ (l16 & 7);
        short8 bv = *(const short8*)&Vs[row * KT + slot * 8];
        Oacc[db] = __builtin_amdgcn_mfma_f32_16x16x32_bf16(pa[s], bv, Oacc[db], 0, 0, 0);
      }
    }
    #pragma unroll
    for (int s = 0; s < 2; ++s)
      Lacc = __builtin_amdgcn_mfma_f32_16x16x32_bf16(pa[s], bv1, Lacc, 0, 0, 0);

    __syncthreads();
  }

  // l for row quad*4+i lives in lane quad*16+0, reg i
  float linv[4];
  #pragma unroll
  for (int i = 0; i < 4; ++i) {
    float lv = __shfl(Lacc[i], quad << 4, 64);
    linv[i] = 1.f / lv;
  }
  #pragma unroll
  for (int i = 0; i < 4; ++i) {
    int n = q0 + wave * 16 + quad * 4 + i;
    size_t row = ((size_t)(b << 10) + n) * DIM + h * HD;
    #pragma unroll
    for (int db = 0; db < 4; ++db) {
      float val = Oacc[db][i] * linv[i];
      unsigned short hv = f2bf(val);
      attn_hi[row + db * 16 + l16] = hv;
      attn_lo[row + db * 16 + l16] = f2bf(val - bf2f(hv));
    }
  }
}

// ---------------------------------------------------------------------------
extern "C" void kernel_launch(void* const* d_in, const int* in_sizes, int n_in,
                              void* d_out, int out_size, void* d_ws, size_t ws_size,
                              hipStream_t stream)
{
  const float* x      = (const float*)d_in[0];   // [8,1024,768]
  const float* qkv_w  = (const float*)d_in[1];   // [2304,768]
  const float* proj_w = (const float*)d_in[2];   // [768,768]
  const float* proj_b = (const float*)d_in[3];   // [768]
  float* out = (float*)d_out;                    // [8,1024,768]

  const int M = BATCH * SEQ;                           // 8192
  const size_t he = (size_t)BATCH * NHEADS * SEQ * HD; // 6.29M = 8192*768

  unsigned short* q_bf  = (unsigned short*)d_ws;
  unsigned short* k_bf  = q_bf + he;
  unsigned short* v_t   = k_bf + he;                   // [b,h,d,n]
  unsigned short* x_bf  = v_t + he;                    // [8192,768] bf16
  unsigned short* qw_bf = x_bf + he;                   // [2304,768] bf16
  unsigned short* pw_hi = qw_bf + (size_t)3 * DIM * DIM;
  unsigned short* pw_lo = pw_hi + (size_t)DIM * DIM;
  unsigned short* a_hi  = pw_lo + (size_t)DIM * DIM;   // attn out hi [8192,768]
  unsigned short* a_lo  = a_hi + he;

  // 0) fused prep
  prep_all<<<(NX4 + NQ4 + NP4 + 255) / 256, 256, 0, stream>>>(
      x, qkv_w, proj_w, x_bf, qw_bf, pw_hi, pw_lo);

  // 1) QKV projection: single-pass bf16 MFMA, glld staging,
  //    writes scaled-q / k [b,h,n,d] and v transposed [b,h,d,n]
  gemm_mfma_glld<128, 1, true><<<dim3(M / 128, 3 * DIM / 128), 256, 0, stream>>>(
      x_bf, nullptr, qw_bf, nullptr, nullptr, q_bf, k_bf, v_t, nullptr);

  // 2) Flash attention (bf16 MFMA, fixed-max softmax, XCD-affine grid)
  flash_attn_mfma<<<dim3(BATCH * NHEADS, SEQ / 64), 256, 0, stream>>>(
      q_bf, k_bf, v_t, a_hi, a_lo);

  // 3) Output projection: 3-pass split-bf16 MFMA + bias, fp32 out
  gemm_mfma_glld<64, 3, false><<<dim3(M / 128, DIM / 64), 256, 0, stream>>>(
      a_hi, a_lo, pw_hi, pw_lo, proj_b, nullptr, nullptr, nullptr, out);
}

// Round 8
// 218.582 us; speedup vs baseline: 1.0194x; 1.0049x over previous
//
#include <hip/hip_runtime.h>
#include <math.h>

constexpr int DIM    = 768;
constexpr int NHEADS = 12;
constexpr int HD     = 64;
constexpr int BATCH  = 8;
constexpr int SEQ    = 1024;
constexpr float SCALE = 0.125f;           // HEAD_DIM^-0.5
constexpr float QSCALE = 0.18033688011112042f;  // SCALE * log2(e), baked into q

typedef __attribute__((ext_vector_type(8))) short short8;   // 8 bf16 (4 VGPRs)
typedef __attribute__((ext_vector_type(4))) float f32x4;    // MFMA accumulator

static __device__ __forceinline__ unsigned short f2bf(float f) {
  unsigned int u = __float_as_uint(f);
  return (unsigned short)((u + 0x7fffu + ((u >> 16) & 1u)) >> 16);  // RNE
}
static __device__ __forceinline__ float bf2f(unsigned short h) {
  return __uint_as_float((unsigned int)h << 16);
}

// async global->LDS, 16B per lane; LDS dest = wave-uniform base + lane*16
#define GLLD16(gp, lp) __builtin_amdgcn_global_load_lds(                    \
    (__attribute__((address_space(1))) void*)(gp),                          \
    (__attribute__((address_space(3))) void*)(lp), 16, 0, 0)

// ---------------------------------------------------------------------------
// Fused prep: convert x and qkv_w to bf16; decompose proj_w to hi/lo.
// ---------------------------------------------------------------------------
constexpr int NX4 = BATCH * SEQ * DIM / 4;      // 1572864
constexpr int NQ4 = 3 * DIM * DIM / 4;          // 442368
constexpr int NP4 = DIM * DIM / 4;              // 147456

__global__ __launch_bounds__(256) void prep_all(
    const float* __restrict__ x, const float* __restrict__ qkv_w,
    const float* __restrict__ proj_w,
    unsigned short* __restrict__ x_bf, unsigned short* __restrict__ qw_bf,
    unsigned short* __restrict__ pw_hi, unsigned short* __restrict__ pw_lo)
{
  int gid = blockIdx.x * 256 + threadIdx.x;
  if (gid < NX4) {
    float4 v = ((const float4*)x)[gid];
    ushort4 h;
    h.x = f2bf(v.x); h.y = f2bf(v.y); h.z = f2bf(v.z); h.w = f2bf(v.w);
    ((ushort4*)x_bf)[gid] = h;
  } else if (gid < NX4 + NQ4) {
    int i = gid - NX4;
    float4 v = ((const float4*)qkv_w)[i];
    ushort4 h;
    h.x = f2bf(v.x); h.y = f2bf(v.y); h.z = f2bf(v.z); h.w = f2bf(v.w);
    ((ushort4*)qw_bf)[i] = h;
  } else if (gid < NX4 + NQ4 + NP4) {
    int i = gid - NX4 - NQ4;
    float4 v = ((const float4*)proj_w)[i];
    ushort4 h, l;
    h.x = f2bf(v.x); l.x = f2bf(v.x - bf2f(h.x));
    h.y = f2bf(v.y); l.y = f2bf(v.y - bf2f(h.y));
    h.z = f2bf(v.z); l.z = f2bf(v.z - bf2f(h.z));
    h.w = f2bf(v.w); l.w = f2bf(v.w - bf2f(h.w));
    ((ushort4*)pw_hi)[i] = h;
    ((ushort4*)pw_lo)[i] = l;
  }
}

// ---------------------------------------------------------------------------
// MFMA GEMM, global_load_lds staging + XOR-swizzled K-chunks.
//   C[M,N] = sum_seg A_seg[M,K] * B_seg[N,K]^T,  K = 768, BK = 64
// Tile 128 x BN, 256 threads = 4 waves (2x2), wave tile 64 x BN/2.
// QKV_EPI: q written *QSCALE-scaled* [b,h,n,d]; k [b,h,n,d]; v TRANSPOSED
//          [b,h,d,n] (packed ushort4 along n).
// ---------------------------------------------------------------------------
template<int BN, int SEGS, bool QKV_EPI>
__global__ __launch_bounds__(256) void gemm_mfma_glld(
    const unsigned short* __restrict__ A0, const unsigned short* __restrict__ A1,
    const unsigned short* __restrict__ B0, const unsigned short* __restrict__ B1,
    const float* __restrict__ bias,
    unsigned short* __restrict__ q_bf, unsigned short* __restrict__ k_bf,
    unsigned short* __restrict__ v_t, float* __restrict__ out)
{
  constexpr int K = DIM, BK = 64;
  constexpr int NB = BN / 32;
  __shared__ __align__(16) unsigned short Abuf[128 * BK];
  __shared__ __align__(16) unsigned short Bbuf[BN * BK];

  const int tid  = threadIdx.x;
  const int wave = tid >> 6, lane = tid & 63;
  const int quad = lane >> 4, l16 = lane & 15;
  const int wm = wave >> 1, wn = wave & 1;
  const int m0 = blockIdx.x * 128, n0 = blockIdx.y * BN;

  f32x4 acc[4][NB] = {};

  #pragma unroll 1
  for (int seg = 0; seg < SEGS; ++seg) {
    const unsigned short* Asrc = (seg == 1) ? A1 : A0;
    const unsigned short* Bsrc = (seg == 2) ? B1 : B0;
    const unsigned short* ga = Asrc + (size_t)m0 * K;
    const unsigned short* gb = Bsrc + (size_t)n0 * K;

    #pragma unroll 1
    for (int k0 = 0; k0 < K; k0 += BK) {
      #pragma unroll
      for (int i = 0; i < 4; ++i) {
        int c = i * 256 + tid;
        int row = c >> 3;
        int col = ((c & 7) ^ (row & 7)) * 8;           // XOR swizzle
        GLLD16(ga + (size_t)row * K + k0 + col,
               Abuf + (size_t)(i * 256 + wave * 64) * 8);
      }
      #pragma unroll
      for (int i = 0; i < BN / 32; ++i) {
        int c = i * 256 + tid;
        int row = c >> 3;
        int col = ((c & 7) ^ (row & 7)) * 8;
        GLLD16(gb + (size_t)row * K + k0 + col,
               Bbuf + (size_t)(i * 256 + wave * 64) * 8);
      }
      __syncthreads();

      #pragma unroll
      for (int s = 0; s < 2; ++s) {
        short8 af[4], bfr[NB];
        #pragma unroll
        for (int mb = 0; mb < 4; ++mb) {
          int row = wm * 64 + mb * 16 + l16;
          int cg = (s * 4 + quad) ^ (row & 7);
          af[mb] = *(const short8*)&Abuf[row * BK + cg * 8];
        }
        #pragma unroll
        for (int nb = 0; nb < NB; ++nb) {
          int row = wn * (BN / 2) + nb * 16 + l16;
          int cg = (s * 4 + quad) ^ (row & 7);
          bfr[nb] = *(const short8*)&Bbuf[row * BK + cg * 8];
        }
        #pragma unroll
        for (int mb = 0; mb < 4; ++mb)
          #pragma unroll
          for (int nb = 0; nb < NB; ++nb)
            acc[mb][nb] = __builtin_amdgcn_mfma_f32_16x16x32_bf16(
                af[mb], bfr[nb], acc[mb][nb], 0, 0, 0);
      }
      __syncthreads();
    }
  }

  if (QKV_EPI) {
    #pragma unroll
    for (int nb = 0; nb < NB; ++nb) {
      int n = n0 + wn * (BN / 2) + nb * 16 + l16;
      int t = n / DIM, rem = n % DIM;   // t uniform per block-column
      int h = rem >> 6, d = rem & 63;
      if (t == 2) {
        // V transposed [b,h,d,n]: 4 consecutive n per lane -> packed store
        #pragma unroll
        for (int mb = 0; mb < 4; ++mb) {
          int mb_base = m0 + wm * 64 + mb * 16 + quad * 4;
          int bb = mb_base >> 10, nn = mb_base & 1023;
          ushort4 s4;
          s4.x = f2bf(acc[mb][nb][0]); s4.y = f2bf(acc[mb][nb][1]);
          s4.z = f2bf(acc[mb][nb][2]); s4.w = f2bf(acc[mb][nb][3]);
          *(ushort4*)&v_t[(((size_t)(bb * NHEADS + h) * HD + d) << 10) + nn] = s4;
        }
      } else {
        unsigned short* dst = (t == 0) ? q_bf : k_bf;
        float sc = (t == 0) ? QSCALE : 1.f;   // bake softmax scale into q
        #pragma unroll
        for (int mb = 0; mb < 4; ++mb) {
          #pragma unroll
          for (int r = 0; r < 4; ++r) {
            int m = m0 + wm * 64 + mb * 16 + quad * 4 + r;
            int bb = m >> 10, nn = m & 1023;
            dst[(((size_t)(bb * NHEADS + h) << 10) + nn) * HD + d] =
                f2bf(acc[mb][nb][r] * sc);
          }
        }
      }
    }
  } else {
    #pragma unroll
    for (int nb = 0; nb < NB; ++nb) {
      int n = n0 + wn * (BN / 2) + nb * 16 + l16;
      float bv = bias[n];
      #pragma unroll
      for (int mb = 0; mb < 4; ++mb) {
        #pragma unroll
        for (int r = 0; r < 4; ++r) {
          int m = m0 + wm * 64 + mb * 16 + quad * 4 + r;
          out[(size_t)m * DIM + n] = acc[mb][nb][r] + bv;
        }
      }
    }
  }
}

// ---------------------------------------------------------------------------
// Flash attention, bf16 MFMA, fixed-max softmax (scores pre-scaled into q;
// p = exp2(s) directly). K [b,h,n,d] and V [b,h,d,n] staged via
// global_load_lds with XOR swizzle. Grid (x=head, y=q-tile) -> XCD-affine.
//
// NEW (R8): compute S^T = K*Q^T (operand swap -- fragments are bit-identical)
// so each lane holds P[q=l16][key=kb*16+quad*4+i]: 4 consecutive keys per kb
// -> Ps round-trip becomes 4x ds_write_b64 (v_perm-packed) instead of
// 16x ds_write_b16 + 16 shifts. PV A-fragment read unchanged.
// ---------------------------------------------------------------------------
__global__ __launch_bounds__(256) void flash_attn_mfma(
    const unsigned short* __restrict__ q_bf,   // [b,h,n,d], pre-scaled
    const unsigned short* __restrict__ k_bf,   // [b,h,n,d]
    const unsigned short* __restrict__ v_t,    // [b,h,d,n]
    unsigned short* __restrict__ attn_hi,
    unsigned short* __restrict__ attn_lo)
{
  constexpr int KT = 64;
  constexpr int PLD = KT + 8;                  // 72 shorts; 144B row stride
  __shared__ __align__(16) unsigned short Ks[KT * HD];     // [key][d] swizzled
  __shared__ __align__(16) unsigned short Vs[HD * KT];     // [d][key] swizzled
  __shared__ __align__(16) unsigned short PsT[4][16][PLD]; // [wave][q][key]

  const int tid  = threadIdx.x;
  const int wave = tid >> 6, lane = tid & 63;
  const int quad = lane >> 4, l16 = lane & 15;
  const int bh = blockIdx.x;                  // head on x -> XCD affinity
  const int b = bh / NHEADS, h = bh % NHEADS;
  const int q0 = blockIdx.y * 64;
  const size_t head_base = (size_t)bh << 16;  // bh * 1024 * 64

  short8 aq[2];
  {
    const unsigned short* qs = q_bf + head_base + (size_t)(q0 + wave * 16 + l16) * HD;
    aq[0] = *(const short8*)&qs[quad * 8];
    aq[1] = *(const short8*)&qs[32 + quad * 8];
  }
  short8 bv1;   // ones column n==0: lane l16==0 holds 1.0 for all k
  {
    short one = (l16 == 0) ? (short)0x3f80 : (short)0;
    #pragma unroll
    for (int j = 0; j < 8; ++j) bv1[j] = one;
  }

  f32x4 Oacc[4] = {};
  f32x4 Lacc = {};

  for (int kt = 0; kt < SEQ / KT; ++kt) {
    const unsigned short* ks = k_bf + head_base + (size_t)kt * KT * HD;
    const unsigned short* vs = v_t + head_base + (size_t)kt * KT;
    #pragma unroll
    for (int i = 0; i < 2; ++i) {
      int c = i * 256 + tid;
      int row = c >> 3;
      int col = ((c & 7) ^ (row & 7)) * 8;
      GLLD16(ks + (size_t)row * HD + col, Ks + (size_t)(i * 256 + wave * 64) * 8);
    }
    #pragma unroll
    for (int i = 0; i < 2; ++i) {
      int c = i * 256 + tid;
      int row = c >> 3;                        // d index
      int col = ((c & 7) ^ (row & 7)) * 8;     // key offset within tile
      GLLD16(vs + (size_t)row * SEQ + col, Vs + (size_t)(i * 256 + wave * 64) * 8);
    }
    __syncthreads();

    // S^T = K * Q^T  (operand-swapped MFMA; same fragments as before)
    // lane holds S[q=l16][key = kb*16 + quad*4 + i] in reg i
    f32x4 Sacc[4] = {};
    #pragma unroll
    for (int kb = 0; kb < 4; ++kb) {
      #pragma unroll
      for (int s = 0; s < 2; ++s) {
        int row = kb * 16 + l16;
        int slot = (s * 4 + quad) ^ (l16 & 7);
        short8 bk = *(const short8*)&Ks[row * HD + slot * 8];
        Sacc[kb] = __builtin_amdgcn_mfma_f32_16x16x32_bf16(bk, aq[s], Sacc[kb], 0, 0, 0);
      }
    }

    // p = 2^s; pack 4 consecutive keys (trunc bf16) -> one b64 store per kb
    #pragma unroll
    for (int kb = 0; kb < 4; ++kb) {
      float p0 = exp2f(Sacc[kb][0]);
      float p1 = exp2f(Sacc[kb][1]);
      float p2 = exp2f(Sacc[kb][2]);
      float p3 = exp2f(Sacc[kb][3]);
      uint2 pk;
      pk.x = __builtin_amdgcn_perm(__float_as_uint(p1), __float_as_uint(p0), 0x07060302u);
      pk.y = __builtin_amdgcn_perm(__float_as_uint(p3), __float_as_uint(p2), 0x07060302u);
      *(uint2*)&PsT[wave][l16][kb * 16 + quad * 4] = pk;
    }

    // O += P*V ; l += P*ones  (same pa operand -> consistency)
    short8 pa[2];
    pa[0] = *(const short8*)&PsT[wave][l16][quad * 8];
    pa[1] = *(const short8*)&PsT[wave][l16][32 + quad * 8];
    #pragma unroll
    for (int db = 0; db < 4; ++db) {
      #pragma unroll
      for (int s = 0; s < 2; ++s) {
        int row = db * 16 + l16;               // d index
        int slot = (s * 4 + quad) ^ (l16 & 7);
        short8 bv = *(const short8*)&Vs[row * KT + slot * 8];
        Oacc[db] = __builtin_amdgcn_mfma_f32_16x16x32_bf16(pa[s], bv, Oacc[db], 0, 0, 0);
      }
    }
    #pragma unroll
    for (int s = 0; s < 2; ++s)
      Lacc = __builtin_amdgcn_mfma_f32_16x16x32_bf16(pa[s], bv1, Lacc, 0, 0, 0);

    __syncthreads();
  }

  // l for row quad*4+i lives in lane quad*16+0, reg i
  float linv[4];
  #pragma unroll
  for (int i = 0; i < 4; ++i) {
    float lv = __shfl(Lacc[i], quad << 4, 64);
    linv[i] = 1.f / lv;
  }
  #pragma unroll
  for (int i = 0; i < 4; ++i) {
    int n = q0 + wave * 16 + quad * 4 + i;
    size_t row = ((size_t)(b << 10) + n) * DIM + h * HD;
    #pragma unroll
    for (int db = 0; db < 4; ++db) {
      float val = Oacc[db][i] * linv[i];
      unsigned short hv = f2bf(val);
      attn_hi[row + db * 16 + l16] = hv;
      attn_lo[row + db * 16 + l16] = f2bf(val - bf2f(hv));
    }
  }
}

// ---------------------------------------------------------------------------
extern "C" void kernel_launch(void* const* d_in, const int* in_sizes, int n_in,
                              void* d_out, int out_size, void* d_ws, size_t ws_size,
                              hipStream_t stream)
{
  const float* x      = (const float*)d_in[0];   // [8,1024,768]
  const float* qkv_w  = (const float*)d_in[1];   // [2304,768]
  const float* proj_w = (const float*)d_in[2];   // [768,768]
  const float* proj_b = (const float*)d_in[3];   // [768]
  float* out = (float*)d_out;                    // [8,1024,768]

  const int M = BATCH * SEQ;                           // 8192
  const size_t he = (size_t)BATCH * NHEADS * SEQ * HD; // 6.29M = 8192*768

  unsigned short* q_bf  = (unsigned short*)d_ws;
  unsigned short* k_bf  = q_bf + he;
  unsigned short* v_t   = k_bf + he;                   // [b,h,d,n]
  unsigned short* x_bf  = v_t + he;                    // [8192,768] bf16
  unsigned short* qw_bf = x_bf + he;                   // [2304,768] bf16
  unsigned short* pw_hi = qw_bf + (size_t)3 * DIM * DIM;
  unsigned short* pw_lo = pw_hi + (size_t)DIM * DIM;
  unsigned short* a_hi  = pw_lo + (size_t)DIM * DIM;   // attn out hi [8192,768]
  unsigned short* a_lo  = a_hi + he;

  // 0) fused prep
  prep_all<<<(NX4 + NQ4 + NP4 + 255) / 256, 256, 0, stream>>>(
      x, qkv_w, proj_w, x_bf, qw_bf, pw_hi, pw_lo);

  // 1) QKV projection: single-pass bf16 MFMA, glld staging,
  //    writes scaled-q / k [b,h,n,d] and v transposed [b,h,d,n]
  gemm_mfma_glld<128, 1, true><<<dim3(M / 128, 3 * DIM / 128), 256, 0, stream>>>(
      x_bf, nullptr, qw_bf, nullptr, nullptr, q_bf, k_bf, v_t, nullptr);

  // 2) Flash attention (bf16 MFMA, S^T softmax path, XCD-affine grid)
  flash_attn_mfma<<<dim3(BATCH * NHEADS, SEQ / 64), 256, 0, stream>>>(
      q_bf, k_bf, v_t, a_hi, a_lo);

  // 3) Output projection: 3-pass split-bf16 MFMA + bias, fp32 out
  gemm_mfma_glld<64, 3, false><<<dim3(M / 128, DIM / 64), 256, 0, stream>>>(
      a_hi, a_lo, pw_hi, pw_lo, proj_b, nullptr, nullptr, nullptr, out);
}

// Round 9
// 198.429 us; speedup vs baseline: 1.1229x; 1.1016x over previous
//
#include <hip/hip_runtime.h>
#include <math.h>

constexpr int DIM    = 768;
constexpr int NHEADS = 12;
constexpr int HD     = 64;
constexpr int BATCH  = 8;
constexpr int SEQ    = 1024;
constexpr float SCALE = 0.125f;           // HEAD_DIM^-0.5
constexpr float QSCALE = 0.18033688011112042f;  // SCALE * log2(e), baked into q

typedef __attribute__((ext_vector_type(8))) short short8;     // 8 bf16
typedef __attribute__((ext_vector_type(8))) _Float16 half8;   // 8 fp16
typedef __attribute__((ext_vector_type(4))) float f32x4;      // MFMA accumulator

static __device__ __forceinline__ unsigned short f2bf(float f) {
  unsigned int u = __float_as_uint(f);
  return (unsigned short)((u + 0x7fffu + ((u >> 16) & 1u)) >> 16);  // RNE
}
static __device__ __forceinline__ float bf2f(unsigned short h) {
  return __uint_as_float((unsigned int)h << 16);
}
static __device__ __forceinline__ unsigned short f2h(float f) {
  _Float16 h = (_Float16)f;                                   // RNE cvt
  return __builtin_bit_cast(unsigned short, h);
}

// async global->LDS, 16B per lane; LDS dest = wave-uniform base + lane*16
#define GLLD16(gp, lp) __builtin_amdgcn_global_load_lds(                    \
    (__attribute__((address_space(1))) void*)(gp),                          \
    (__attribute__((address_space(3))) void*)(lp), 16, 0, 0)

// ---------------------------------------------------------------------------
// Fused prep: x, qkv_w -> bf16;  proj_w -> fp16 (single-pass proj GEMM).
// ---------------------------------------------------------------------------
constexpr int NX4 = BATCH * SEQ * DIM / 4;      // 1572864
constexpr int NQ4 = 3 * DIM * DIM / 4;          // 442368
constexpr int NP4 = DIM * DIM / 4;              // 147456

__global__ __launch_bounds__(256) void prep_all(
    const float* __restrict__ x, const float* __restrict__ qkv_w,
    const float* __restrict__ proj_w,
    unsigned short* __restrict__ x_bf, unsigned short* __restrict__ qw_bf,
    unsigned short* __restrict__ pw_h)
{
  int gid = blockIdx.x * 256 + threadIdx.x;
  if (gid < NX4) {
    float4 v = ((const float4*)x)[gid];
    ushort4 h;
    h.x = f2bf(v.x); h.y = f2bf(v.y); h.z = f2bf(v.z); h.w = f2bf(v.w);
    ((ushort4*)x_bf)[gid] = h;
  } else if (gid < NX4 + NQ4) {
    int i = gid - NX4;
    float4 v = ((const float4*)qkv_w)[i];
    ushort4 h;
    h.x = f2bf(v.x); h.y = f2bf(v.y); h.z = f2bf(v.z); h.w = f2bf(v.w);
    ((ushort4*)qw_bf)[i] = h;
  } else if (gid < NX4 + NQ4 + NP4) {
    int i = gid - NX4 - NQ4;
    float4 v = ((const float4*)proj_w)[i];
    ushort4 h;
    h.x = f2h(v.x); h.y = f2h(v.y); h.z = f2h(v.z); h.w = f2h(v.w);
    ((ushort4*)pw_h)[i] = h;
  }
}

// ---------------------------------------------------------------------------
// MFMA GEMM, global_load_lds staging + XOR-swizzled K-chunks.
//   C[M,N] = sum_seg A_seg[M,K] * B_seg[N,K]^T,  K = 768, BK = 64
// Tile 128 x BN, 256 threads = 4 waves (2x2), wave tile 64 x BN/2.
// FP16=false: bf16 MFMA; FP16=true: fp16 MFMA (same rate & C/D layout).
// QKV_EPI: q *QSCALE-scaled* [b,h,n,d]; k [b,h,n,d]; v transposed [b,h,d,n].
// ---------------------------------------------------------------------------
template<int BN, int SEGS, bool QKV_EPI, bool FP16>
__global__ __launch_bounds__(256) void gemm_mfma_glld(
    const unsigned short* __restrict__ A0, const unsigned short* __restrict__ A1,
    const unsigned short* __restrict__ B0, const unsigned short* __restrict__ B1,
    const float* __restrict__ bias,
    unsigned short* __restrict__ q_bf, unsigned short* __restrict__ k_bf,
    unsigned short* __restrict__ v_t, float* __restrict__ out)
{
  constexpr int K = DIM, BK = 64;
  constexpr int NB = BN / 32;
  __shared__ __align__(16) unsigned short Abuf[128 * BK];
  __shared__ __align__(16) unsigned short Bbuf[BN * BK];

  const int tid  = threadIdx.x;
  const int wave = tid >> 6, lane = tid & 63;
  const int quad = lane >> 4, l16 = lane & 15;
  const int wm = wave >> 1, wn = wave & 1;
  const int m0 = blockIdx.x * 128, n0 = blockIdx.y * BN;

  f32x4 acc[4][NB] = {};

  #pragma unroll 1
  for (int seg = 0; seg < SEGS; ++seg) {
    const unsigned short* Asrc = (seg == 1) ? A1 : A0;
    const unsigned short* Bsrc = (seg == 2) ? B1 : B0;
    const unsigned short* ga = Asrc + (size_t)m0 * K;
    const unsigned short* gb = Bsrc + (size_t)n0 * K;

    #pragma unroll 1
    for (int k0 = 0; k0 < K; k0 += BK) {
      #pragma unroll
      for (int i = 0; i < 4; ++i) {
        int c = i * 256 + tid;
        int row = c >> 3;
        int col = ((c & 7) ^ (row & 7)) * 8;           // XOR swizzle
        GLLD16(ga + (size_t)row * K + k0 + col,
               Abuf + (size_t)(i * 256 + wave * 64) * 8);
      }
      #pragma unroll
      for (int i = 0; i < BN / 32; ++i) {
        int c = i * 256 + tid;
        int row = c >> 3;
        int col = ((c & 7) ^ (row & 7)) * 8;
        GLLD16(gb + (size_t)row * K + k0 + col,
               Bbuf + (size_t)(i * 256 + wave * 64) * 8);
      }
      __syncthreads();

      #pragma unroll
      for (int s = 0; s < 2; ++s) {
        short8 af[4], bfr[NB];
        #pragma unroll
        for (int mb = 0; mb < 4; ++mb) {
          int row = wm * 64 + mb * 16 + l16;
          int cg = (s * 4 + quad) ^ (row & 7);
          af[mb] = *(const short8*)&Abuf[row * BK + cg * 8];
        }
        #pragma unroll
        for (int nb = 0; nb < NB; ++nb) {
          int row = wn * (BN / 2) + nb * 16 + l16;
          int cg = (s * 4 + quad) ^ (row & 7);
          bfr[nb] = *(const short8*)&Bbuf[row * BK + cg * 8];
        }
        #pragma unroll
        for (int mb = 0; mb < 4; ++mb)
          #pragma unroll
          for (int nb = 0; nb < NB; ++nb) {
            if (FP16)
              acc[mb][nb] = __builtin_amdgcn_mfma_f32_16x16x32_f16(
                  __builtin_bit_cast(half8, af[mb]),
                  __builtin_bit_cast(half8, bfr[nb]), acc[mb][nb], 0, 0, 0);
            else
              acc[mb][nb] = __builtin_amdgcn_mfma_f32_16x16x32_bf16(
                  af[mb], bfr[nb], acc[mb][nb], 0, 0, 0);
          }
      }
      __syncthreads();
    }
  }

  if (QKV_EPI) {
    #pragma unroll
    for (int nb = 0; nb < NB; ++nb) {
      int n = n0 + wn * (BN / 2) + nb * 16 + l16;
      int t = n / DIM, rem = n % DIM;   // t uniform per block-column
      int h = rem >> 6, d = rem & 63;
      if (t == 2) {
        // V transposed [b,h,d,n]: 4 consecutive n per lane -> packed store
        #pragma unroll
        for (int mb = 0; mb < 4; ++mb) {
          int mb_base = m0 + wm * 64 + mb * 16 + quad * 4;
          int bb = mb_base >> 10, nn = mb_base & 1023;
          ushort4 s4;
          s4.x = f2bf(acc[mb][nb][0]); s4.y = f2bf(acc[mb][nb][1]);
          s4.z = f2bf(acc[mb][nb][2]); s4.w = f2bf(acc[mb][nb][3]);
          *(ushort4*)&v_t[(((size_t)(bb * NHEADS + h) * HD + d) << 10) + nn] = s4;
        }
      } else {
        unsigned short* dst = (t == 0) ? q_bf : k_bf;
        float sc = (t == 0) ? QSCALE : 1.f;   // bake softmax scale into q
        #pragma unroll
        for (int mb = 0; mb < 4; ++mb) {
          #pragma unroll
          for (int r = 0; r < 4; ++r) {
            int m = m0 + wm * 64 + mb * 16 + quad * 4 + r;
            int bb = m >> 10, nn = m & 1023;
            dst[(((size_t)(bb * NHEADS + h) << 10) + nn) * HD + d] =
                f2bf(acc[mb][nb][r] * sc);
          }
        }
      }
    }
  } else {
    #pragma unroll
    for (int nb = 0; nb < NB; ++nb) {
      int n = n0 + wn * (BN / 2) + nb * 16 + l16;
      float bv = bias[n];
      #pragma unroll
      for (int mb = 0; mb < 4; ++mb) {
        #pragma unroll
        for (int r = 0; r < 4; ++r) {
          int m = m0 + wm * 64 + mb * 16 + quad * 4 + r;
          out[(size_t)m * DIM + n] = acc[mb][nb][r] + bv;
        }
      }
    }
  }
}

// ---------------------------------------------------------------------------
// Flash attention, bf16 MFMA, fixed-max softmax (scores pre-scaled into q;
// p = exp2(s)). K [b,h,n,d], V [b,h,d,n] staged via global_load_lds + XOR
// swizzle. Grid (x=head, y=q-tile) -> XCD-affine K/V reuse (R7-measured).
// S^T = K*Q^T operand-swap -> packed b64 Ps stores (R8).
// Epilogue writes fp16 attention output (single array) for the fp16 proj.
// ---------------------------------------------------------------------------
__global__ __launch_bounds__(256) void flash_attn_mfma(
    const unsigned short* __restrict__ q_bf,   // [b,h,n,d], pre-scaled
    const unsigned short* __restrict__ k_bf,   // [b,h,n,d]
    const unsigned short* __restrict__ v_t,    // [b,h,d,n]
    unsigned short* __restrict__ a_f16)        // [b,n,h*64+d] fp16
{
  constexpr int KT = 64;
  constexpr int PLD = KT + 8;                  // 72 shorts; 144B row stride
  __shared__ __align__(16) unsigned short Ks[KT * HD];     // [key][d] swizzled
  __shared__ __align__(16) unsigned short Vs[HD * KT];     // [d][key] swizzled
  __shared__ __align__(16) unsigned short PsT[4][16][PLD]; // [wave][q][key]

  const int tid  = threadIdx.x;
  const int wave = tid >> 6, lane = tid & 63;
  const int quad = lane >> 4, l16 = lane & 15;
  const int bh = blockIdx.x;                  // head on x -> XCD affinity
  const int b = bh / NHEADS, h = bh % NHEADS;
  const int q0 = blockIdx.y * 64;
  const size_t head_base = (size_t)bh << 16;  // bh * 1024 * 64

  short8 aq[2];
  {
    const unsigned short* qs = q_bf + head_base + (size_t)(q0 + wave * 16 + l16) * HD;
    aq[0] = *(const short8*)&qs[quad * 8];
    aq[1] = *(const short8*)&qs[32 + quad * 8];
  }
  short8 bv1;   // ones column n==0: lane l16==0 holds 1.0 for all k
  {
    short one = (l16 == 0) ? (short)0x3f80 : (short)0;
    #pragma unroll
    for (int j = 0; j < 8; ++j) bv1[j] = one;
  }

  f32x4 Oacc[4] = {};
  f32x4 Lacc = {};

  for (int kt = 0; kt < SEQ / KT; ++kt) {
    const unsigned short* ks = k_bf + head_base + (size_t)kt * KT * HD;
    const unsigned short* vs = v_t + head_base + (size_t)kt * KT;
    #pragma unroll
    for (int i = 0; i < 2; ++i) {
      int c = i * 256 + tid;
      int row = c >> 3;
      int col = ((c & 7) ^ (row & 7)) * 8;
      GLLD16(ks + (size_t)row * HD + col, Ks + (size_t)(i * 256 + wave * 64) * 8);
    }
    #pragma unroll
    for (int i = 0; i < 2; ++i) {
      int c = i * 256 + tid;
      int row = c >> 3;                        // d index
      int col = ((c & 7) ^ (row & 7)) * 8;     // key offset within tile
      GLLD16(vs + (size_t)row * SEQ + col, Vs + (size_t)(i * 256 + wave * 64) * 8);
    }
    __syncthreads();

    // S^T = K * Q^T: lane holds S[q=l16][key = kb*16 + quad*4 + i]
    f32x4 Sacc[4] = {};
    #pragma unroll
    for (int kb = 0; kb < 4; ++kb) {
      #pragma unroll
      for (int s = 0; s < 2; ++s) {
        int row = kb * 16 + l16;
        int slot = (s * 4 + quad) ^ (l16 & 7);
        short8 bk = *(const short8*)&Ks[row * HD + slot * 8];
        Sacc[kb] = __builtin_amdgcn_mfma_f32_16x16x32_bf16(bk, aq[s], Sacc[kb], 0, 0, 0);
      }
    }

    // p = 2^s; pack 4 consecutive keys (trunc bf16) -> one b64 store per kb
    #pragma unroll
    for (int kb = 0; kb < 4; ++kb) {
      float p0 = exp2f(Sacc[kb][0]);
      float p1 = exp2f(Sacc[kb][1]);
      float p2 = exp2f(Sacc[kb][2]);
      float p3 = exp2f(Sacc[kb][3]);
      uint2 pk;
      pk.x = __builtin_amdgcn_perm(__float_as_uint(p1), __float_as_uint(p0), 0x07060302u);
      pk.y = __builtin_amdgcn_perm(__float_as_uint(p3), __float_as_uint(p2), 0x07060302u);
      *(uint2*)&PsT[wave][l16][kb * 16 + quad * 4] = pk;
    }

    // O += P*V ; l += P*ones  (same pa operand -> consistency)
    short8 pa[2];
    pa[0] = *(const short8*)&PsT[wave][l16][quad * 8];
    pa[1] = *(const short8*)&PsT[wave][l16][32 + quad * 8];
    #pragma unroll
    for (int db = 0; db < 4; ++db) {
      #pragma unroll
      for (int s = 0; s < 2; ++s) {
        int row = db * 16 + l16;               // d index
        int slot = (s * 4 + quad) ^ (l16 & 7);
        short8 bv = *(const short8*)&Vs[row * KT + slot * 8];
        Oacc[db] = __builtin_amdgcn_mfma_f32_16x16x32_bf16(pa[s], bv, Oacc[db], 0, 0, 0);
      }
    }
    #pragma unroll
    for (int s = 0; s < 2; ++s)
      Lacc = __builtin_amdgcn_mfma_f32_16x16x32_bf16(pa[s], bv1, Lacc, 0, 0, 0);

    __syncthreads();
  }

  // l for row quad*4+i lives in lane quad*16+0, reg i
  float linv[4];
  #pragma unroll
  for (int i = 0; i < 4; ++i) {
    float lv = __shfl(Lacc[i], quad << 4, 64);
    linv[i] = 1.f / lv;
  }
  #pragma unroll
  for (int i = 0; i < 4; ++i) {
    int n = q0 + wave * 16 + quad * 4 + i;
    size_t row = ((size_t)(b << 10) + n) * DIM + h * HD;
    #pragma unroll
    for (int db = 0; db < 4; ++db)
      a_f16[row + db * 16 + l16] = f2h(Oacc[db][i] * linv[i]);
  }
}

// ---------------------------------------------------------------------------
extern "C" void kernel_launch(void* const* d_in, const int* in_sizes, int n_in,
                              void* d_out, int out_size, void* d_ws, size_t ws_size,
                              hipStream_t stream)
{
  const float* x      = (const float*)d_in[0];   // [8,1024,768]
  const float* qkv_w  = (const float*)d_in[1];   // [2304,768]
  const float* proj_w = (const float*)d_in[2];   // [768,768]
  const float* proj_b = (const float*)d_in[3];   // [768]
  float* out = (float*)d_out;                    // [8,1024,768]

  const int M = BATCH * SEQ;                           // 8192
  const size_t he = (size_t)BATCH * NHEADS * SEQ * HD; // 6.29M = 8192*768

  unsigned short* q_bf  = (unsigned short*)d_ws;
  unsigned short* k_bf  = q_bf + he;
  unsigned short* v_t   = k_bf + he;                   // [b,h,d,n]
  unsigned short* x_bf  = v_t + he;                    // [8192,768] bf16
  unsigned short* qw_bf = x_bf + he;                   // [2304,768] bf16
  unsigned short* pw_h  = qw_bf + (size_t)3 * DIM * DIM;  // [768,768] fp16
  unsigned short* a_f16 = pw_h + (size_t)DIM * DIM;    // [8192,768] fp16

  // 0) fused prep
  prep_all<<<(NX4 + NQ4 + NP4 + 255) / 256, 256, 0, stream>>>(
      x, qkv_w, proj_w, x_bf, qw_bf, pw_h);

  // 1) QKV projection: single-pass bf16 MFMA, glld staging,
  //    writes scaled-q / k [b,h,n,d] and v transposed [b,h,d,n]
  gemm_mfma_glld<128, 1, true, false><<<dim3(M / 128, 3 * DIM / 128), 256, 0, stream>>>(
      x_bf, nullptr, qw_bf, nullptr, nullptr, q_bf, k_bf, v_t, nullptr);

  // 2) Flash attention (bf16 MFMA, S^T path, XCD-affine grid, fp16 out)
  flash_attn_mfma<<<dim3(BATCH * NHEADS, SEQ / 64), 256, 0, stream>>>(
      q_bf, k_bf, v_t, a_f16);

  // 3) Output projection: SINGLE-pass fp16 MFMA + bias, fp32 out
  gemm_mfma_glld<64, 1, false, true><<<dim3(M / 128, DIM / 64), 256, 0, stream>>>(
      a_f16, nullptr, pw_h, nullptr, proj_b, nullptr, nullptr, nullptr, out);
}